// Round 12
// baseline (178.058 us; speedup 1.0000x reference)
//
#include <hip/hip_runtime.h>
#include <hip/hip_bf16.h>
#include <hip/hip_fp16.h>
#include <math.h>

#define N 1024
#define F 256
#define H 64

typedef __attribute__((ext_vector_type(8))) _Float16 f16x8;
typedef __attribute__((ext_vector_type(4))) unsigned int u32x4;
typedef __attribute__((ext_vector_type(4))) float f32x4;

__device__ __forceinline__ float wave_reduce_sum(float v) {
#pragma unroll
  for (int off = 32; off; off >>= 1) v += __shfl_xor(v, off, 64);
  return v;
}

__device__ __forceinline__ unsigned int hpack(float a, float b) {
  __half ha = __float2half(a), hb = __float2half(b);
  unsigned short ua = __builtin_bit_cast(unsigned short, ha);
  unsigned short ub = __builtin_bit_cast(unsigned short, hb);
  return (unsigned int)ua | ((unsigned int)ub << 16);
}

// packed |a-b| on 2xf16
__device__ __forceinline__ unsigned int absdiff2(unsigned int a, unsigned int b) {
  __half2 ah = __builtin_bit_cast(__half2, a);
  __half2 bh = __builtin_bit_cast(__half2, b);
  __half2 d = __hsub2(ah, bh);
  return __builtin_bit_cast(unsigned int, d) & 0x7FFF7FFFu;
}

// ---------------- k1: FUSED input_proj + qkv (blocks 0..255) AND prep (blocks 256..259)
__global__ __launch_bounds__(256) void k_input_qkv_prep(
    const float* __restrict__ feat, const float* __restrict__ w1,
    const float* __restrict__ b1, const float* __restrict__ lng,
    const float* __restrict__ lnb, const float* __restrict__ w2,
    const float* __restrict__ b2, const float* __restrict__ aw,
    const float* __restrict__ abias, const float* __restrict__ pg1,
    const float* __restrict__ pv1, float* __restrict__ h, float* __restrict__ Qh,
    float* __restrict__ Kh, float* __restrict__ Vh, float* __restrict__ WgA,
    float* __restrict__ WgB, float* __restrict__ WvA, float* __restrict__ WvB,
    unsigned int* __restrict__ WF, int* __restrict__ flags) {
  if (blockIdx.x >= 256) {
    // ---- prep part: weight combos + W4^T f16 MFMA fragments + zero merge flags
    const int pb = blockIdx.x - 256;  // 0..3
    const int tid = threadIdx.x;
    flags[pb * 256 + tid] = 0;
#pragma unroll
    for (int c = 0; c < 4; ++c) {
      int idx = (pb * 4 + c) * 256 + tid;  // 0..4095 == k*64+l
      float g1 = pg1[idx];
      float g2 = pg1[4096 + idx];
      float g3 = pg1[8192 + idx];
      WgA[idx] = g1 + g3;
      WgB[idx] = g2 - g3;
      float v1 = pv1[idx];
      float v2 = pv1[4096 + idx];
      float v3 = pv1[8192 + idx];
      WvA[idx] = v1 + v3;
      WvB[idx] = v2 - v3;
    }
    const int sub = tid >> 6;
    const int lane = tid & 63;
    const int b = pb * 4 + sub;  // 0..15 = mat*8 + ks*4 + Mt
    const float* W = (b & 8) ? pv1 : pg1;
    const int Mt = b & 3;
    const int ks = (b >> 2) & 1;
    const int l = Mt * 16 + (lane & 15);
    const int kb = 192 + ks * 32 + (lane >> 4) * 8;  // |diff| block = rows 192..255
    uint4 o;
    o.x = hpack(W[(kb + 0) * H + l], W[(kb + 1) * H + l]);
    o.y = hpack(W[(kb + 2) * H + l], W[(kb + 3) * H + l]);
    o.z = hpack(W[(kb + 4) * H + l], W[(kb + 5) * H + l]);
    o.w = hpack(W[(kb + 6) * H + l], W[(kb + 7) * H + l]);
    ((uint4*)WF)[b * 64 + lane] = o;
    return;
  }
  // ---- input_proj + qkv (4 rows per block; wave = row)
  const int sub = threadIdx.x >> 6, lane = threadIdx.x & 63;
  const int row = blockIdx.x * 4 + sub;
  __shared__ float frow[4][F];
#pragma unroll
  for (int c = 0; c < 4; ++c) frow[sub][c * 64 + lane] = feat[row * F + c * 64 + lane];
  __syncthreads();
  float acc = b1[lane];
#pragma unroll 8
  for (int k = 0; k < F; ++k) acc += frow[sub][k] * w1[k * H + lane];
  float mu = wave_reduce_sum(acc) * (1.f / 64.f);
  float d = acc - mu;
  float var = wave_reduce_sum(d * d) * (1.f / 64.f);
  float y = d * rsqrtf(var + 1e-5f) * lng[lane] + lnb[lane];
  y = fmaxf(y, 0.f);
  __shared__ float yrow[4][H];
  yrow[sub][lane] = y;
  __syncthreads();
  float acc2 = b2[lane];
#pragma unroll 8
  for (int k = 0; k < H; ++k) acc2 += yrow[sub][k] * w2[k * H + lane];
  float hv = fmaxf(acc2, 0.f);
  h[row * H + lane] = hv;
  __shared__ float hrow[4][H];
  hrow[sub][lane] = hv;
  __syncthreads();
  float a0 = abias[lane], a1 = abias[64 + lane], a2 = abias[128 + lane];
#pragma unroll 8
  for (int k = 0; k < H; ++k) {
    float hk = hrow[sub][k];
    a0 += hk * aw[k * 192 + lane];
    a1 += hk * aw[k * 192 + 64 + lane];
    a2 += hk * aw[k * 192 + 128 + lane];
  }
  const int base = (lane >> 4) * (N * 16) + row * 16 + (lane & 15);
  Qh[base] = a0;
  Kh[base] = a1;
  Vh[base] = a2;
}

// ---------------- k2: attention — LDS-staged K/V tiles shared by 4 q-waves.
__global__ __launch_bounds__(256) void k_attn2(const float* __restrict__ Qh,
                                               const float* __restrict__ Kh,
                                               const float* __restrict__ Vh,
                                               float* __restrict__ o) {
  const int head = blockIdx.x >> 8;
  const int i0 = (blockIdx.x & 255) * 4;
  const int tid = threadIdx.x;
  const int q2 = tid >> 6, js = tid & 63;
  const int i = i0 + q2;

  const float* qp = Qh + head * (N * 16) + i * 16;
  const float4 q0 = *(const float4*)(qp);
  const float4 q1 = *(const float4*)(qp + 4);
  const float4 q2v = *(const float4*)(qp + 8);
  const float4 q3 = *(const float4*)(qp + 12);
  const float* kb = Kh + head * (N * 16);
  const float* vb = Vh + head * (N * 16);

  __shared__ float4 kt[2][4][64];  // [buf][seg][row]
  __shared__ float4 vt[2][4][64];
  const int sr = tid & 63, sg = tid >> 6;  // stage coords: row, segment
  kt[0][sg][sr] = *(const float4*)(kb + sr * 16 + sg * 4);
  vt[0][sg][sr] = *(const float4*)(vb + sr * 16 + sg * 4);
  __syncthreads();

  float m = -3.0e38f, s = 0.f;
  float4 c0 = {0, 0, 0, 0}, c1 = {0, 0, 0, 0}, c2 = {0, 0, 0, 0}, c3 = {0, 0, 0, 0};

#pragma unroll 1
  for (int t = 0; t < 16; ++t) {
    const int cur = t & 1;
    if (t < 15) {  // prefetch next tile into the other buffer
      const int jr = (t + 1) * 64 + sr;
      kt[cur ^ 1][sg][sr] = *(const float4*)(kb + jr * 16 + sg * 4);
      vt[cur ^ 1][sg][sr] = *(const float4*)(vb + jr * 16 + sg * 4);
    }
    const float4 k0 = kt[cur][0][js], k1 = kt[cur][1][js];
    const float4 k2 = kt[cur][2][js], k3 = kt[cur][3][js];
    const float4 v0 = vt[cur][0][js], v1 = vt[cur][1][js];
    const float4 v2 = vt[cur][2][js], v3 = vt[cur][3][js];

    float sc = q0.x * k0.x + q0.y * k0.y + q0.z * k0.z + q0.w * k0.w;
    sc += q1.x * k1.x + q1.y * k1.y + q1.z * k1.z + q1.w * k1.w;
    sc += q2v.x * k2.x + q2v.y * k2.y + q2v.z * k2.z + q2v.w * k2.w;
    sc += q3.x * k3.x + q3.y * k3.y + q3.z * k3.z + q3.w * k3.w;
    sc *= 0.25f;  // 1/sqrt(16)

    float mn = fmaxf(m, sc);
    float cc = __expf(m - mn);
    float p = __expf(sc - mn);
    s = s * cc + p;
    m = mn;
    c0.x = c0.x * cc + p * v0.x; c0.y = c0.y * cc + p * v0.y;
    c0.z = c0.z * cc + p * v0.z; c0.w = c0.w * cc + p * v0.w;
    c1.x = c1.x * cc + p * v1.x; c1.y = c1.y * cc + p * v1.y;
    c1.z = c1.z * cc + p * v1.z; c1.w = c1.w * cc + p * v1.w;
    c2.x = c2.x * cc + p * v2.x; c2.y = c2.y * cc + p * v2.y;
    c2.z = c2.z * cc + p * v2.z; c2.w = c2.w * cc + p * v2.w;
    c3.x = c3.x * cc + p * v3.x; c3.y = c3.y * cc + p * v3.y;
    c3.z = c3.z * cc + p * v3.z; c3.w = c3.w * cc + p * v3.w;
    __syncthreads();
  }

  float M = m, S = s;
#pragma unroll
  for (int off = 32; off; off >>= 1) {
    float Mo = __shfl_xor(M, off, 64);
    float So = __shfl_xor(S, off, 64);
    float Mn = fmaxf(M, Mo);
    S = S * __expf(M - Mn) + So * __expf(Mo - Mn);
    M = Mn;
  }
  const float wgt = __expf(m - M) / S;

  __shared__ float lds[4][64][17];
  float* lp = &lds[q2][js][0];
  lp[0] = c0.x * wgt;  lp[1] = c0.y * wgt;  lp[2] = c0.z * wgt;  lp[3] = c0.w * wgt;
  lp[4] = c1.x * wgt;  lp[5] = c1.y * wgt;  lp[6] = c1.z * wgt;  lp[7] = c1.w * wgt;
  lp[8] = c2.x * wgt;  lp[9] = c2.y * wgt;  lp[10] = c2.z * wgt; lp[11] = c2.w * wgt;
  lp[12] = c3.x * wgt; lp[13] = c3.y * wgt; lp[14] = c3.z * wgt; lp[15] = c3.w * wgt;
  __syncthreads();

  if (tid < 64) {
    const int q = tid >> 4, d = tid & 15;
    float sum = 0.f;
#pragma unroll
    for (int k = 0; k < 64; ++k) sum += lds[q][k][d];
    o[(i0 + q) * H + head * 16 + d] = sum;
  }
}

// ---------------- k3: FUSED attn_out + LN + per-row projections + f16 enc (4 rows/block)
__global__ __launch_bounds__(256) void k_attn_ab(
    const float* __restrict__ o, const float* __restrict__ w, const float* __restrict__ b,
    const float* __restrict__ h, const float* __restrict__ lng,
    const float* __restrict__ lnb, const float* __restrict__ WgA,
    const float* __restrict__ WgB, const float* __restrict__ WvA,
    const float* __restrict__ WvB, const float* __restrict__ pg_b1,
    const float* __restrict__ pv_b1, float* __restrict__ enc, float* __restrict__ Ag,
    float* __restrict__ Av, float* __restrict__ Pg, float* __restrict__ Pv,
    unsigned int* __restrict__ encH) {
  const int sub = threadIdx.x >> 6, lane = threadIdx.x & 63;
  const int row = blockIdx.x * 4 + sub;
  __shared__ float orow[4][H];
  orow[sub][lane] = o[row * H + lane];
  __syncthreads();
  float a = b[lane];
#pragma unroll 8
  for (int k = 0; k < H; ++k) a += orow[sub][k] * w[k * H + lane];
  float x = h[row * H + lane] + a;
  float mu = wave_reduce_sum(x) * (1.f / 64.f);
  float d = x - mu;
  float var = wave_reduce_sum(d * d) * (1.f / 64.f);
  float e = d * rsqrtf(var + 1e-5f) * lng[lane] + lnb[lane];
  enc[row * H + lane] = e;
  __shared__ float erow[4][H];
  erow[sub][lane] = e;
  __syncthreads();
  if (lane < 32) encH[row * 32 + lane] = hpack(erow[sub][2 * lane], erow[sub][2 * lane + 1]);
  float ag = pg_b1[lane], bg = 0.f, av = pv_b1[lane], bv = 0.f;
#pragma unroll 4
  for (int k = 0; k < H; ++k) {
    float ev = erow[sub][k];
    ag += ev * WgA[k * H + lane];
    bg += ev * WgB[k * H + lane];
    av += ev * WvA[k * H + lane];
    bv += ev * WvB[k * H + lane];
  }
  Ag[row * H + lane] = ag;
  Av[row * H + lane] = av;
  int idx = (((row >> 4) * 4 + (lane >> 4)) * 4 + ((lane >> 2) & 3)) * 64 +
            (row & 15) * 4 + (lane & 3);
  Pg[idx] = bg;
  Pv[idx] = bv;
}

// ---------------- k4: PAIR PARTIAL (f16 MFMA) + fused last-block merge/LN epilogue.
// Hot loop is R9's exact proven body (VGPR 128); merge added post-loop only.
__global__ __launch_bounds__(128) void k_pairp(
    const unsigned int* __restrict__ encH, const float* __restrict__ Ag,
    const float* __restrict__ Av, const unsigned int* __restrict__ WF,
    const float* __restrict__ Pg, const float* __restrict__ Pv,
    const float* __restrict__ pg_w2, const float* __restrict__ pg_b2,
    float* __restrict__ Pm, float* __restrict__ Ps,
    float* __restrict__ Pctx0, float* __restrict__ Pctx1,
    const float* __restrict__ enc, const float* __restrict__ pv_w2,
    const float* __restrict__ pv_b2, const float* __restrict__ lng,
    const float* __restrict__ lnb, float* __restrict__ enc2,
    int* __restrict__ flags) {
  const int bid = blockIdx.x;
  const int i = bid & (N - 1);
  const int half = bid >> 10;
  const int tid = threadIdx.x;
  const int lane = tid & 63;
  const int w = tid >> 6;  // 0/1: quarter within this half
  const int l15 = lane & 15, g4 = lane >> 4;
  const float LOG2E = 1.44269504088896f;

  f16x8 wg[2][4], wv[2][4];
  const uint4* WF4 = (const uint4*)WF;
#pragma unroll
  for (int ks = 0; ks < 2; ++ks)
#pragma unroll
    for (int Mt = 0; Mt < 4; ++Mt) {
      wg[ks][Mt] = __builtin_bit_cast(f16x8, WF4[(ks * 4 + Mt) * 64 + lane]);
      wv[ks][Mt] = __builtin_bit_cast(f16x8, WF4[((2 + ks) * 4 + Mt) * 64 + lane]);
    }

  // ei: packed f16, 8 u32 (16 k-values) per lane
  const uint4* eH = (const uint4*)encH + (size_t)i * 8;
  const uint4 eiL = eH[g4];
  const uint4 eiU = eH[4 + g4];

  f32x4 agv[4], avv[4];
  float4 w2s[4];
#pragma unroll
  for (int Mt = 0; Mt < 4; ++Mt) {
    float4 t = *(const float4*)(Ag + i * H + Mt * 16 + g4 * 4);
    agv[Mt] = f32x4{t.x, t.y, t.z, t.w};
    float4 u = *(const float4*)(Av + i * H + Mt * 16 + g4 * 4);
    avv[Mt] = f32x4{u.x, u.y, u.z, u.w};
    float4 ww = *(const float4*)(pg_w2 + Mt * 16 + g4 * 4);
    w2s[Mt] = make_float4(ww.x * LOG2E, ww.y * LOG2E, ww.z * LOG2E, ww.w * LOG2E);
  }
  const float b2g = pg_b2[0] * LOG2E;

  float m = -3.0e38f, s = 0.f;
  float ctx[16];
#pragma unroll
  for (int e = 0; e < 16; ++e) ctx[e] = 0.f;

  const int jbase = half * 512 + w * 256;
  const uint4* ejp = (const uint4*)encH + (size_t)(jbase + l15) * 8;
  uint4 na = ejp[g4];
  uint4 nc = ejp[4 + g4];

#pragma unroll 1
  for (int t = 0; t < 16; ++t) {
    const int j0 = jbase + t * 16;
    const int pbase = ((j0 >> 4) * 16 + g4) * 64 + l15 * 4;
    // gate-side B terms (needed right after cg MFMAs)
    float4 pg0 = *(const float4*)(Pg + pbase);
    float4 pg1 = *(const float4*)(Pg + pbase + 256);
    float4 pg2 = *(const float4*)(Pg + pbase + 512);
    float4 pg3 = *(const float4*)(Pg + pbase + 768);

    // B fragments: |ei - ej| in packed f16 (8 pk_sub + 8 and)
    u32x4 t0 = {absdiff2(eiL.x, na.x), absdiff2(eiL.y, na.y),
                absdiff2(eiL.z, na.z), absdiff2(eiL.w, na.w)};
    u32x4 t1 = {absdiff2(eiU.x, nc.x), absdiff2(eiU.y, nc.y),
                absdiff2(eiU.z, nc.z), absdiff2(eiU.w, nc.w)};
    f16x8 b0 = __builtin_bit_cast(f16x8, t0);
    f16x8 b1 = __builtin_bit_cast(f16x8, t1);
    // prefetch next tile's ej (last-iter overread stays inside d_ws: unused)
    ejp += 16 * 8;
    na = ejp[g4];
    nc = ejp[4 + g4];

    f32x4 cg[4], cv[4];
#pragma unroll
    for (int Mt = 0; Mt < 4; ++Mt) {
      cg[Mt] = __builtin_amdgcn_mfma_f32_16x16x32_f16(wg[0][Mt], b0, agv[Mt], 0, 0, 0);
      cg[Mt] = __builtin_amdgcn_mfma_f32_16x16x32_f16(wg[1][Mt], b1, cg[Mt], 0, 0, 0);
      cv[Mt] = __builtin_amdgcn_mfma_f32_16x16x32_f16(wv[0][Mt], b0, avv[Mt], 0, 0, 0);
      cv[Mt] = __builtin_amdgcn_mfma_f32_16x16x32_f16(wv[1][Mt], b1, cv[Mt], 0, 0, 0);
    }

    // val-side B terms: issue now, consumed after gate epilogue (latency hidden)
    float4 pv0 = *(const float4*)(Pv + pbase);
    float4 pv1 = *(const float4*)(Pv + pbase + 256);
    float4 pv2 = *(const float4*)(Pv + pbase + 512);
    float4 pv3 = *(const float4*)(Pv + pbase + 768);

    // gate (log2 domain): 4 independent fma chains, then pairwise sum
    float ga = fmaxf(cg[0][0] + pg0.x, 0.f) * w2s[0].x;
    float gb = fmaxf(cg[0][1] + pg0.y, 0.f) * w2s[0].y;
    float gc = fmaxf(cg[0][2] + pg0.z, 0.f) * w2s[0].z;
    float gd = fmaxf(cg[0][3] + pg0.w, 0.f) * w2s[0].w;
    ga = fmaf(fmaxf(cg[1][0] + pg1.x, 0.f), w2s[1].x, ga);
    gb = fmaf(fmaxf(cg[1][1] + pg1.y, 0.f), w2s[1].y, gb);
    gc = fmaf(fmaxf(cg[1][2] + pg1.z, 0.f), w2s[1].z, gc);
    gd = fmaf(fmaxf(cg[1][3] + pg1.w, 0.f), w2s[1].w, gd);
    ga = fmaf(fmaxf(cg[2][0] + pg2.x, 0.f), w2s[2].x, ga);
    gb = fmaf(fmaxf(cg[2][1] + pg2.y, 0.f), w2s[2].y, gb);
    gc = fmaf(fmaxf(cg[2][2] + pg2.z, 0.f), w2s[2].z, gc);
    gd = fmaf(fmaxf(cg[2][3] + pg2.w, 0.f), w2s[2].w, gd);
    ga = fmaf(fmaxf(cg[3][0] + pg3.x, 0.f), w2s[3].x, ga);
    gb = fmaf(fmaxf(cg[3][1] + pg3.y, 0.f), w2s[3].y, gb);
    gc = fmaf(fmaxf(cg[3][2] + pg3.z, 0.f), w2s[3].z, gc);
    gd = fmaf(fmaxf(cg[3][3] + pg3.w, 0.f), w2s[3].w, gd);
    float gate = (ga + gb) + (gc + gd);
    gate += __shfl_xor(gate, 16, 64);
    gate += __shfl_xor(gate, 32, 64);
    gate += b2g;
    if (j0 + l15 == i) gate = -3.0e38f;  // diagonal mask

    float p;
    if (__any(gate > m + 8.f)) {  // rescale only when some lane's max grew
      float mn = fmaxf(m, gate);
      float c = exp2f(m - mn);
      p = exp2f(gate - mn);
      s *= c;
      m = mn;
#pragma unroll
      for (int e = 0; e < 16; ++e) ctx[e] *= c;
    } else {
      p = exp2f(gate - m);  // bounded by 2^8
    }
    s += p;
    ctx[0]  = fmaf(p, fmaxf(cv[0][0] + pv0.x, 0.f), ctx[0]);
    ctx[1]  = fmaf(p, fmaxf(cv[0][1] + pv0.y, 0.f), ctx[1]);
    ctx[2]  = fmaf(p, fmaxf(cv[0][2] + pv0.z, 0.f), ctx[2]);
    ctx[3]  = fmaf(p, fmaxf(cv[0][3] + pv0.w, 0.f), ctx[3]);
    ctx[4]  = fmaf(p, fmaxf(cv[1][0] + pv1.x, 0.f), ctx[4]);
    ctx[5]  = fmaf(p, fmaxf(cv[1][1] + pv1.y, 0.f), ctx[5]);
    ctx[6]  = fmaf(p, fmaxf(cv[1][2] + pv1.z, 0.f), ctx[6]);
    ctx[7]  = fmaf(p, fmaxf(cv[1][3] + pv1.w, 0.f), ctx[7]);
    ctx[8]  = fmaf(p, fmaxf(cv[2][0] + pv2.x, 0.f), ctx[8]);
    ctx[9]  = fmaf(p, fmaxf(cv[2][1] + pv2.y, 0.f), ctx[9]);
    ctx[10] = fmaf(p, fmaxf(cv[2][2] + pv2.z, 0.f), ctx[10]);
    ctx[11] = fmaf(p, fmaxf(cv[2][3] + pv2.w, 0.f), ctx[11]);
    ctx[12] = fmaf(p, fmaxf(cv[3][0] + pv3.x, 0.f), ctx[12]);
    ctx[13] = fmaf(p, fmaxf(cv[3][1] + pv3.y, 0.f), ctx[13]);
    ctx[14] = fmaf(p, fmaxf(cv[3][2] + pv3.z, 0.f), ctx[14]);
    ctx[15] = fmaf(p, fmaxf(cv[3][3] + pv3.w, 0.f), ctx[15]);
  }

  // in-wave flash-merge across the 16 j-columns (xor butterfly over lane&15)
#pragma unroll
  for (int off = 1; off <= 8; off <<= 1) {
    float mo = __shfl_xor(m, off, 64);
    float so = __shfl_xor(s, off, 64);
    float M2 = fmaxf(m, mo);
    float ca = exp2f(m - M2);
    float cb = exp2f(mo - M2);
    s = s * ca + so * cb;
#pragma unroll
    for (int e = 0; e < 16; ++e) {
      float co = __shfl_xor(ctx[e], off, 64);
      ctx[e] = ctx[e] * ca + co * cb;
    }
    m = M2;
  }

  __shared__ float ctxs[2][64];
  __shared__ float mss[2][2];
  if (l15 == 0) {
#pragma unroll
    for (int Mt = 0; Mt < 4; ++Mt)
#pragma unroll
      for (int r = 0; r < 4; ++r) ctxs[w][Mt * 16 + g4 * 4 + r] = ctx[Mt * 4 + r];
  }
  if (lane == 0) {
    mss[w][0] = m;
    mss[w][1] = s;
  }
  __syncthreads();

  if (w == 0) {
    float m0 = mss[0][0], s0 = mss[0][1], m1 = mss[1][0], s1 = mss[1][1];
    float M = fmaxf(m0, m1);
    float e0 = exp2f(m0 - M), e1 = exp2f(m1 - M);
    float S = s0 * e0 + s1 * e1;
    float cm = ctxs[0][lane] * e0 + ctxs[1][lane] * e1;  // unnormalized
    float* dst = half ? Pctx1 : Pctx0;
    dst[i * H + lane] = cm;
    if (lane == 0) {
      Pm[bid] = M;
      Ps[bid] = S;
    }
    // ---- last-block-done merge: second finisher for row i merges + LN -> enc2
    __threadfence();  // release our partial
    int oldv = 0;
    if (lane == 0) oldv = atomicAdd(&flags[i], 1);
    oldv = __shfl(oldv, 0, 64);
    if (oldv == 1) {
      __threadfence();  // acquire other half's partial
      float am = Pm[i], as = Ps[i], bm = Pm[N + i], bs = Ps[N + i];
      float ca = Pctx0[i * H + lane];
      float cb = Pctx1[i * H + lane];  // aliases enc2: read-before-write below
      float MM = fmaxf(am, bm);
      float ea = exp2f(am - MM), eb = exp2f(bm - MM);
      float SS = as * ea + bs * eb;
      float cp = (ca * ea + cb * eb) / SS;
      float pc = pv_b2[lane];
#pragma unroll 8
      for (int k = 0; k < 64; ++k) pc += __shfl(cp, k, 64) * pv_w2[k * H + lane];
      float x = enc[i * H + lane] + pc;
      float mu2 = wave_reduce_sum(x) * (1.f / 64.f);
      float dd = x - mu2;
      float var2 = wave_reduce_sum(dd * dd) * (1.f / 64.f);
      enc2[i * H + lane] = dd * rsqrtf(var2 + 1e-5f) * lng[lane] + lnb[lane];
    }
  }
}

// ---------------- k5: score head with in-block column mean (4 rows per block)
__global__ __launch_bounds__(256) void k_score(
    const float* __restrict__ enc2, const float* __restrict__ sh_w1,
    const float* __restrict__ sh_b1, const float* __restrict__ sh_w2,
    const float* __restrict__ sh_b2, float* __restrict__ out) {
  const int sub = threadIdx.x >> 6, lane = threadIdx.x & 63;
  const int row = blockIdx.x * 4 + sub;
  // column sum: wave sub covers rows sub*256 .. sub*256+255
  float cs = 0.f;
  const float* pp = enc2 + (sub * 256) * H + lane;
#pragma unroll 8
  for (int r = 0; r < 256; ++r) cs += pp[r * H];
  __shared__ float part[4][64];
  __shared__ float erow[4][H];
  part[sub][lane] = cs;
  erow[sub][lane] = enc2[row * H + lane];
  __syncthreads();
  float g = (part[0][lane] + part[1][lane] + part[2][lane] + part[3][lane]) * (1.f / N);
  float t = sh_b1[lane];
#pragma unroll 8
  for (int k = 0; k < 64; ++k) {
    t += erow[sub][k] * sh_w1[k * H + lane];
    t += __shfl(g, k, 64) * sh_w1[(64 + k) * H + lane];
  }
  t = fmaxf(t, 0.f);
  float prt = t * sh_w2[lane];
  float sum = wave_reduce_sum(prt);
  if (lane == 0) out[row] = sum + sh_b2[0];
}

extern "C" void kernel_launch(void* const* d_in, const int* in_sizes, int n_in,
                              void* d_out, int out_size, void* d_ws, size_t ws_size,
                              hipStream_t stream) {
  const float* feat = (const float*)d_in[0];
  const float* ip_w1 = (const float*)d_in[1];
  const float* ip_b1 = (const float*)d_in[2];
  const float* ip_ln_g = (const float*)d_in[3];
  const float* ip_ln_b = (const float*)d_in[4];
  const float* ip_w2 = (const float*)d_in[5];
  const float* ip_b2 = (const float*)d_in[6];
  const float* attn_in_w = (const float*)d_in[7];
  const float* attn_in_b = (const float*)d_in[8];
  const float* attn_out_w = (const float*)d_in[9];
  const float* attn_out_b = (const float*)d_in[10];
  const float* attn_ln_g = (const float*)d_in[11];
  const float* attn_ln_b = (const float*)d_in[12];
  const float* pg_w1 = (const float*)d_in[13];
  const float* pg_b1 = (const float*)d_in[14];
  const float* pg_w2 = (const float*)d_in[15];
  const float* pg_b2 = (const float*)d_in[16];
  const float* pv_w1 = (const float*)d_in[17];
  const float* pv_b1 = (const float*)d_in[18];
  const float* pv_w2 = (const float*)d_in[19];
  const float* pv_b2 = (const float*)d_in[20];
  const float* ctx_ln_g = (const float*)d_in[21];
  const float* ctx_ln_b = (const float*)d_in[22];
  const float* sh_w1 = (const float*)d_in[23];
  const float* sh_b1 = (const float*)d_in[24];
  const float* sh_w2 = (const float*)d_in[25];
  const float* sh_b2 = (const float*)d_in[26];

  float* ws = (float*)d_ws;
  // lifetimes: h written k1, read k3 (Av aliases h: k3 same-row read-then-write);
  // Qh/Kh/Vh written k1, read k2, then Pg/Pv/Ag overwrite in k3; o written k2, read k3,
  // then Pctx0 (k4) reuses it; Pctx1 aliases enc2 (k4-merge reads partial then writes).
  float* h = ws;                        // 0      .. 65536
  float* Qh = ws + 65536;
  float* Kh = ws + 131072;
  float* Vh = ws + 196608;
  float* o = ws + 262144;
  float* enc = ws + 327680;
  float* enc2 = ws + 393216;
  float* Pg = ws + 65536;               // reuse Qh
  float* Pv = ws + 131072;              // reuse Kh
  float* Ag = ws + 196608;              // reuse Vh
  float* Av = ws;                       // reuse h (same-row read-then-write in k3)
  float* Pctx0 = ws + 262144;           // reuse o
  float* Pctx1 = enc2;                  // merge reads partial then overwrites same slot
  float* WgA = ws + 458752;             // 4096 each
  float* WgB = ws + 462848;
  float* WvA = ws + 466944;
  float* WvB = ws + 471040;
  unsigned int* WF = (unsigned int*)(ws + 475136);  // 4096 u32
  float* Pm = ws + 479232;              // 2048
  float* Ps = ws + 481280;              // 2048
  unsigned int* encH = (unsigned int*)(ws + 483328);  // 32768 u32 (f16-packed enc)
  int* flags = (int*)(ws + 516096);     // 1024 ints (zeroed each call by k1 prep blocks)
  float* out = (float*)d_out;

  k_input_qkv_prep<<<260, 256, 0, stream>>>(feat, ip_w1, ip_b1, ip_ln_g, ip_ln_b, ip_w2,
                                            ip_b2, attn_in_w, attn_in_b, pg_w1, pv_w1, h,
                                            Qh, Kh, Vh, WgA, WgB, WvA, WvB, WF, flags);
  k_attn2<<<1024, 256, 0, stream>>>(Qh, Kh, Vh, o);
  k_attn_ab<<<256, 256, 0, stream>>>(o, attn_out_w, attn_out_b, h, attn_ln_g, attn_ln_b,
                                     WgA, WgB, WvA, WvB, pg_b1, pv_b1, enc, Ag, Av, Pg,
                                     Pv, encH);
  k_pairp<<<2 * N, 128, 0, stream>>>(encH, Ag, Av, WF, Pg, Pv, pg_w2, pg_b2, Pm, Ps,
                                     Pctx0, Pctx1, enc, pv_w2, pv_b2, ctx_ln_g, ctx_ln_b,
                                     enc2, flags);
  k_score<<<256, 256, 0, stream>>>(enc2, sh_w1, sh_b1, sh_w2, sh_b2, out);
}

// Round 14
// 94.231 us; speedup vs baseline: 1.8896x; 1.8896x over previous
//
#include <hip/hip_runtime.h>
#include <hip/hip_bf16.h>
#include <hip/hip_fp16.h>
#include <math.h>

#define N 1024
#define F 256
#define H 64

typedef __attribute__((ext_vector_type(8))) _Float16 f16x8;
typedef __attribute__((ext_vector_type(4))) unsigned int u32x4;
typedef __attribute__((ext_vector_type(4))) float f32x4;

__device__ __forceinline__ float wave_reduce_sum(float v) {
#pragma unroll
  for (int off = 32; off; off >>= 1) v += __shfl_xor(v, off, 64);
  return v;
}

__device__ __forceinline__ unsigned int hpack(float a, float b) {
  __half ha = __float2half(a), hb = __float2half(b);
  unsigned short ua = __builtin_bit_cast(unsigned short, ha);
  unsigned short ub = __builtin_bit_cast(unsigned short, hb);
  return (unsigned int)ua | ((unsigned int)ub << 16);
}

// packed |a-b| on 2xf16
__device__ __forceinline__ unsigned int absdiff2(unsigned int a, unsigned int b) {
  __half2 ah = __builtin_bit_cast(__half2, a);
  __half2 bh = __builtin_bit_cast(__half2, b);
  __half2 d = __hsub2(ah, bh);
  return __builtin_bit_cast(unsigned int, d) & 0x7FFF7FFFu;
}

// ---------------- k1: FUSED input_proj + qkv (blocks 0..255) AND prep (blocks 256..259)
__global__ __launch_bounds__(256) void k_input_qkv_prep(
    const float* __restrict__ feat, const float* __restrict__ w1,
    const float* __restrict__ b1, const float* __restrict__ lng,
    const float* __restrict__ lnb, const float* __restrict__ w2,
    const float* __restrict__ b2, const float* __restrict__ aw,
    const float* __restrict__ abias, const float* __restrict__ pg1,
    const float* __restrict__ pv1, float* __restrict__ h, float* __restrict__ Qh,
    float* __restrict__ Kh, float* __restrict__ Vh, float* __restrict__ WgA,
    float* __restrict__ WgB, float* __restrict__ WvA, float* __restrict__ WvB,
    unsigned int* __restrict__ WF) {
  if (blockIdx.x >= 256) {
    // ---- prep part: weight combos + W4^T f16 MFMA fragments
    const int pb = blockIdx.x - 256;  // 0..3
    const int tid = threadIdx.x;
#pragma unroll
    for (int c = 0; c < 4; ++c) {
      int idx = (pb * 4 + c) * 256 + tid;  // 0..4095 == k*64+l
      float g1 = pg1[idx];
      float g2 = pg1[4096 + idx];
      float g3 = pg1[8192 + idx];
      WgA[idx] = g1 + g3;
      WgB[idx] = g2 - g3;
      float v1 = pv1[idx];
      float v2 = pv1[4096 + idx];
      float v3 = pv1[8192 + idx];
      WvA[idx] = v1 + v3;
      WvB[idx] = v2 - v3;
    }
    const int sub = tid >> 6;
    const int lane = tid & 63;
    const int b = pb * 4 + sub;  // 0..15 = mat*8 + ks*4 + Mt
    const float* W = (b & 8) ? pv1 : pg1;
    const int Mt = b & 3;
    const int ks = (b >> 2) & 1;
    const int l = Mt * 16 + (lane & 15);
    const int kb = 192 + ks * 32 + (lane >> 4) * 8;  // |diff| block = rows 192..255
    uint4 o;
    o.x = hpack(W[(kb + 0) * H + l], W[(kb + 1) * H + l]);
    o.y = hpack(W[(kb + 2) * H + l], W[(kb + 3) * H + l]);
    o.z = hpack(W[(kb + 4) * H + l], W[(kb + 5) * H + l]);
    o.w = hpack(W[(kb + 6) * H + l], W[(kb + 7) * H + l]);
    ((uint4*)WF)[b * 64 + lane] = o;
    return;
  }
  // ---- input_proj + qkv (4 rows per block; wave = row)
  const int sub = threadIdx.x >> 6, lane = threadIdx.x & 63;
  const int row = blockIdx.x * 4 + sub;
  __shared__ float frow[4][F];
#pragma unroll
  for (int c = 0; c < 4; ++c) frow[sub][c * 64 + lane] = feat[row * F + c * 64 + lane];
  __syncthreads();
  float acc = b1[lane];
#pragma unroll 8
  for (int k = 0; k < F; ++k) acc += frow[sub][k] * w1[k * H + lane];
  float mu = wave_reduce_sum(acc) * (1.f / 64.f);
  float d = acc - mu;
  float var = wave_reduce_sum(d * d) * (1.f / 64.f);
  float y = d * rsqrtf(var + 1e-5f) * lng[lane] + lnb[lane];
  y = fmaxf(y, 0.f);
  __shared__ float yrow[4][H];
  yrow[sub][lane] = y;
  __syncthreads();
  float acc2 = b2[lane];
#pragma unroll 8
  for (int k = 0; k < H; ++k) acc2 += yrow[sub][k] * w2[k * H + lane];
  float hv = fmaxf(acc2, 0.f);
  h[row * H + lane] = hv;
  __shared__ float hrow[4][H];
  hrow[sub][lane] = hv;
  __syncthreads();
  float a0 = abias[lane], a1 = abias[64 + lane], a2 = abias[128 + lane];
#pragma unroll 8
  for (int k = 0; k < H; ++k) {
    float hk = hrow[sub][k];
    a0 += hk * aw[k * 192 + lane];
    a1 += hk * aw[k * 192 + 64 + lane];
    a2 += hk * aw[k * 192 + 128 + lane];
  }
  const int base = (lane >> 4) * (N * 16) + row * 16 + (lane & 15);
  Qh[base] = a0;
  Kh[base] = a1;
  Vh[base] = a2;
}

// ---------------- k2: attention — LDS-staged K/V tiles shared by 4 q-waves.
__global__ __launch_bounds__(256) void k_attn2(const float* __restrict__ Qh,
                                               const float* __restrict__ Kh,
                                               const float* __restrict__ Vh,
                                               float* __restrict__ o) {
  const int head = blockIdx.x >> 8;
  const int i0 = (blockIdx.x & 255) * 4;
  const int tid = threadIdx.x;
  const int q2 = tid >> 6, js = tid & 63;
  const int i = i0 + q2;

  const float* qp = Qh + head * (N * 16) + i * 16;
  const float4 q0 = *(const float4*)(qp);
  const float4 q1 = *(const float4*)(qp + 4);
  const float4 q2v = *(const float4*)(qp + 8);
  const float4 q3 = *(const float4*)(qp + 12);
  const float* kb = Kh + head * (N * 16);
  const float* vb = Vh + head * (N * 16);

  __shared__ float4 kt[2][4][64];  // [buf][seg][row]
  __shared__ float4 vt[2][4][64];
  const int sr = tid & 63, sg = tid >> 6;  // stage coords: row, segment
  kt[0][sg][sr] = *(const float4*)(kb + sr * 16 + sg * 4);
  vt[0][sg][sr] = *(const float4*)(vb + sr * 16 + sg * 4);
  __syncthreads();

  float m = -3.0e38f, s = 0.f;
  float4 c0 = {0, 0, 0, 0}, c1 = {0, 0, 0, 0}, c2 = {0, 0, 0, 0}, c3 = {0, 0, 0, 0};

#pragma unroll 1
  for (int t = 0; t < 16; ++t) {
    const int cur = t & 1;
    if (t < 15) {  // prefetch next tile into the other buffer
      const int jr = (t + 1) * 64 + sr;
      kt[cur ^ 1][sg][sr] = *(const float4*)(kb + jr * 16 + sg * 4);
      vt[cur ^ 1][sg][sr] = *(const float4*)(vb + jr * 16 + sg * 4);
    }
    const float4 k0 = kt[cur][0][js], k1 = kt[cur][1][js];
    const float4 k2 = kt[cur][2][js], k3 = kt[cur][3][js];
    const float4 v0 = vt[cur][0][js], v1 = vt[cur][1][js];
    const float4 v2 = vt[cur][2][js], v3 = vt[cur][3][js];

    float sc = q0.x * k0.x + q0.y * k0.y + q0.z * k0.z + q0.w * k0.w;
    sc += q1.x * k1.x + q1.y * k1.y + q1.z * k1.z + q1.w * k1.w;
    sc += q2v.x * k2.x + q2v.y * k2.y + q2v.z * k2.z + q2v.w * k2.w;
    sc += q3.x * k3.x + q3.y * k3.y + q3.z * k3.z + q3.w * k3.w;
    sc *= 0.25f;  // 1/sqrt(16)

    float mn = fmaxf(m, sc);
    float cc = __expf(m - mn);
    float p = __expf(sc - mn);
    s = s * cc + p;
    m = mn;
    c0.x = c0.x * cc + p * v0.x; c0.y = c0.y * cc + p * v0.y;
    c0.z = c0.z * cc + p * v0.z; c0.w = c0.w * cc + p * v0.w;
    c1.x = c1.x * cc + p * v1.x; c1.y = c1.y * cc + p * v1.y;
    c1.z = c1.z * cc + p * v1.z; c1.w = c1.w * cc + p * v1.w;
    c2.x = c2.x * cc + p * v2.x; c2.y = c2.y * cc + p * v2.y;
    c2.z = c2.z * cc + p * v2.z; c2.w = c2.w * cc + p * v2.w;
    c3.x = c3.x * cc + p * v3.x; c3.y = c3.y * cc + p * v3.y;
    c3.z = c3.z * cc + p * v3.z; c3.w = c3.w * cc + p * v3.w;
    __syncthreads();
  }

  float M = m, S = s;
#pragma unroll
  for (int off = 32; off; off >>= 1) {
    float Mo = __shfl_xor(M, off, 64);
    float So = __shfl_xor(S, off, 64);
    float Mn = fmaxf(M, Mo);
    S = S * __expf(M - Mn) + So * __expf(Mo - Mn);
    M = Mn;
  }
  const float wgt = __expf(m - M) / S;

  __shared__ float lds[4][64][17];
  float* lp = &lds[q2][js][0];
  lp[0] = c0.x * wgt;  lp[1] = c0.y * wgt;  lp[2] = c0.z * wgt;  lp[3] = c0.w * wgt;
  lp[4] = c1.x * wgt;  lp[5] = c1.y * wgt;  lp[6] = c1.z * wgt;  lp[7] = c1.w * wgt;
  lp[8] = c2.x * wgt;  lp[9] = c2.y * wgt;  lp[10] = c2.z * wgt; lp[11] = c2.w * wgt;
  lp[12] = c3.x * wgt; lp[13] = c3.y * wgt; lp[14] = c3.z * wgt; lp[15] = c3.w * wgt;
  __syncthreads();

  if (tid < 64) {
    const int q = tid >> 4, d = tid & 15;
    float sum = 0.f;
#pragma unroll
    for (int k = 0; k < 64; ++k) sum += lds[q][k][d];
    o[(i0 + q) * H + head * 16 + d] = sum;
  }
}

// ---------------- k3: FUSED attn_out + LN + per-row projections + f16 enc (4 rows/block)
// NOTE: h and Av intentionally ALIAS (same ws region, per-thread read-then-write) —
// they must NOT be __restrict__-qualified, or the compiler may reorder the store.
__global__ __launch_bounds__(256) void k_attn_ab(
    const float* __restrict__ o, const float* __restrict__ w, const float* __restrict__ b,
    const float* h, const float* __restrict__ lng,
    const float* __restrict__ lnb, const float* __restrict__ WgA,
    const float* __restrict__ WgB, const float* __restrict__ WvA,
    const float* __restrict__ WvB, const float* __restrict__ pg_b1,
    const float* __restrict__ pv_b1, float* __restrict__ enc, float* __restrict__ Ag,
    float* Av, float* __restrict__ Pg, float* __restrict__ Pv,
    unsigned int* __restrict__ encH) {
  const int sub = threadIdx.x >> 6, lane = threadIdx.x & 63;
  const int row = blockIdx.x * 4 + sub;
  __shared__ float orow[4][H];
  orow[sub][lane] = o[row * H + lane];
  __syncthreads();
  float a = b[lane];
#pragma unroll 8
  for (int k = 0; k < H; ++k) a += orow[sub][k] * w[k * H + lane];
  float x = h[row * H + lane] + a;
  float mu = wave_reduce_sum(x) * (1.f / 64.f);
  float d = x - mu;
  float var = wave_reduce_sum(d * d) * (1.f / 64.f);
  float e = d * rsqrtf(var + 1e-5f) * lng[lane] + lnb[lane];
  enc[row * H + lane] = e;
  __shared__ float erow[4][H];
  erow[sub][lane] = e;
  __syncthreads();
  if (lane < 32) encH[row * 32 + lane] = hpack(erow[sub][2 * lane], erow[sub][2 * lane + 1]);
  float ag = pg_b1[lane], bg = 0.f, av = pv_b1[lane], bv = 0.f;
#pragma unroll 4
  for (int k = 0; k < H; ++k) {
    float ev = erow[sub][k];
    ag += ev * WgA[k * H + lane];
    bg += ev * WgB[k * H + lane];
    av += ev * WvA[k * H + lane];
    bv += ev * WvB[k * H + lane];
  }
  Ag[row * H + lane] = ag;
  Av[row * H + lane] = av;  // aliases h[row*H+lane]; h was read above (ordered: no restrict)
  int idx = (((row >> 4) * 4 + (lane >> 4)) * 4 + ((lane >> 2) & 3)) * 64 +
            (row & 15) * 4 + (lane & 3);
  Pg[idx] = bg;
  Pv[idx] = bv;
}

// ---------------- k4: PAIR PARTIAL (f16 MFMA) — R9's proven body (VGPR 128, no setprio).
__global__ __launch_bounds__(128) void k_pairp(
    const unsigned int* __restrict__ encH, const float* __restrict__ Ag,
    const float* __restrict__ Av, const unsigned int* __restrict__ WF,
    const float* __restrict__ Pg, const float* __restrict__ Pv,
    const float* __restrict__ pg_w2, const float* __restrict__ pg_b2,
    float* __restrict__ Pm, float* __restrict__ Ps,
    float* __restrict__ Pctx0, float* __restrict__ Pctx1) {
  const int bid = blockIdx.x;
  const int i = bid & (N - 1);
  const int half = bid >> 10;
  const int tid = threadIdx.x;
  const int lane = tid & 63;
  const int w = tid >> 6;  // 0/1: quarter within this half
  const int l15 = lane & 15, g4 = lane >> 4;
  const float LOG2E = 1.44269504088896f;

  f16x8 wg[2][4], wv[2][4];
  const uint4* WF4 = (const uint4*)WF;
#pragma unroll
  for (int ks = 0; ks < 2; ++ks)
#pragma unroll
    for (int Mt = 0; Mt < 4; ++Mt) {
      wg[ks][Mt] = __builtin_bit_cast(f16x8, WF4[(ks * 4 + Mt) * 64 + lane]);
      wv[ks][Mt] = __builtin_bit_cast(f16x8, WF4[((2 + ks) * 4 + Mt) * 64 + lane]);
    }

  // ei: packed f16, 8 u32 (16 k-values) per lane
  const uint4* eH = (const uint4*)encH + (size_t)i * 8;
  const uint4 eiL = eH[g4];
  const uint4 eiU = eH[4 + g4];

  f32x4 agv[4], avv[4];
  float4 w2s[4];
#pragma unroll
  for (int Mt = 0; Mt < 4; ++Mt) {
    float4 t = *(const float4*)(Ag + i * H + Mt * 16 + g4 * 4);
    agv[Mt] = f32x4{t.x, t.y, t.z, t.w};
    float4 u = *(const float4*)(Av + i * H + Mt * 16 + g4 * 4);
    avv[Mt] = f32x4{u.x, u.y, u.z, u.w};
    float4 ww = *(const float4*)(pg_w2 + Mt * 16 + g4 * 4);
    w2s[Mt] = make_float4(ww.x * LOG2E, ww.y * LOG2E, ww.z * LOG2E, ww.w * LOG2E);
  }
  const float b2g = pg_b2[0] * LOG2E;

  float m = -3.0e38f, s = 0.f;
  float ctx[16];
#pragma unroll
  for (int e = 0; e < 16; ++e) ctx[e] = 0.f;

  const int jbase = half * 512 + w * 256;
  const uint4* ejp = (const uint4*)encH + (size_t)(jbase + l15) * 8;
  uint4 na = ejp[g4];
  uint4 nc = ejp[4 + g4];

#pragma unroll 1
  for (int t = 0; t < 16; ++t) {
    const int j0 = jbase + t * 16;
    const int pbase = ((j0 >> 4) * 16 + g4) * 64 + l15 * 4;
    // gate-side B terms (needed right after cg MFMAs)
    float4 pg0 = *(const float4*)(Pg + pbase);
    float4 pg1 = *(const float4*)(Pg + pbase + 256);
    float4 pg2 = *(const float4*)(Pg + pbase + 512);
    float4 pg3 = *(const float4*)(Pg + pbase + 768);

    // B fragments: |ei - ej| in packed f16 (8 pk_sub + 8 and)
    u32x4 t0 = {absdiff2(eiL.x, na.x), absdiff2(eiL.y, na.y),
                absdiff2(eiL.z, na.z), absdiff2(eiL.w, na.w)};
    u32x4 t1 = {absdiff2(eiU.x, nc.x), absdiff2(eiU.y, nc.y),
                absdiff2(eiU.z, nc.z), absdiff2(eiU.w, nc.w)};
    f16x8 b0 = __builtin_bit_cast(f16x8, t0);
    f16x8 b1 = __builtin_bit_cast(f16x8, t1);
    // prefetch next tile's ej (last-iter overread stays inside d_ws: unused)
    ejp += 16 * 8;
    na = ejp[g4];
    nc = ejp[4 + g4];

    f32x4 cg[4], cv[4];
#pragma unroll
    for (int Mt = 0; Mt < 4; ++Mt) {
      cg[Mt] = __builtin_amdgcn_mfma_f32_16x16x32_f16(wg[0][Mt], b0, agv[Mt], 0, 0, 0);
      cg[Mt] = __builtin_amdgcn_mfma_f32_16x16x32_f16(wg[1][Mt], b1, cg[Mt], 0, 0, 0);
      cv[Mt] = __builtin_amdgcn_mfma_f32_16x16x32_f16(wv[0][Mt], b0, avv[Mt], 0, 0, 0);
      cv[Mt] = __builtin_amdgcn_mfma_f32_16x16x32_f16(wv[1][Mt], b1, cv[Mt], 0, 0, 0);
    }

    // val-side B terms: issue now, consumed after gate epilogue (latency hidden)
    float4 pv0 = *(const float4*)(Pv + pbase);
    float4 pv1 = *(const float4*)(Pv + pbase + 256);
    float4 pv2 = *(const float4*)(Pv + pbase + 512);
    float4 pv3 = *(const float4*)(Pv + pbase + 768);

    // gate (log2 domain): 4 independent fma chains, then pairwise sum
    float ga = fmaxf(cg[0][0] + pg0.x, 0.f) * w2s[0].x;
    float gb = fmaxf(cg[0][1] + pg0.y, 0.f) * w2s[0].y;
    float gc = fmaxf(cg[0][2] + pg0.z, 0.f) * w2s[0].z;
    float gd = fmaxf(cg[0][3] + pg0.w, 0.f) * w2s[0].w;
    ga = fmaf(fmaxf(cg[1][0] + pg1.x, 0.f), w2s[1].x, ga);
    gb = fmaf(fmaxf(cg[1][1] + pg1.y, 0.f), w2s[1].y, gb);
    gc = fmaf(fmaxf(cg[1][2] + pg1.z, 0.f), w2s[1].z, gc);
    gd = fmaf(fmaxf(cg[1][3] + pg1.w, 0.f), w2s[1].w, gd);
    ga = fmaf(fmaxf(cg[2][0] + pg2.x, 0.f), w2s[2].x, ga);
    gb = fmaf(fmaxf(cg[2][1] + pg2.y, 0.f), w2s[2].y, gb);
    gc = fmaf(fmaxf(cg[2][2] + pg2.z, 0.f), w2s[2].z, gc);
    gd = fmaf(fmaxf(cg[2][3] + pg2.w, 0.f), w2s[2].w, gd);
    ga = fmaf(fmaxf(cg[3][0] + pg3.x, 0.f), w2s[3].x, ga);
    gb = fmaf(fmaxf(cg[3][1] + pg3.y, 0.f), w2s[3].y, gb);
    gc = fmaf(fmaxf(cg[3][2] + pg3.z, 0.f), w2s[3].z, gc);
    gd = fmaf(fmaxf(cg[3][3] + pg3.w, 0.f), w2s[3].w, gd);
    float gate = (ga + gb) + (gc + gd);
    gate += __shfl_xor(gate, 16, 64);
    gate += __shfl_xor(gate, 32, 64);
    gate += b2g;
    if (j0 + l15 == i) gate = -3.0e38f;  // diagonal mask

    float p;
    if (__any(gate > m + 8.f)) {  // rescale only when some lane's max grew
      float mn = fmaxf(m, gate);
      float c = exp2f(m - mn);
      p = exp2f(gate - mn);
      s *= c;
      m = mn;
#pragma unroll
      for (int e = 0; e < 16; ++e) ctx[e] *= c;
    } else {
      p = exp2f(gate - m);  // bounded by 2^8
    }
    s += p;
    ctx[0]  = fmaf(p, fmaxf(cv[0][0] + pv0.x, 0.f), ctx[0]);
    ctx[1]  = fmaf(p, fmaxf(cv[0][1] + pv0.y, 0.f), ctx[1]);
    ctx[2]  = fmaf(p, fmaxf(cv[0][2] + pv0.z, 0.f), ctx[2]);
    ctx[3]  = fmaf(p, fmaxf(cv[0][3] + pv0.w, 0.f), ctx[3]);
    ctx[4]  = fmaf(p, fmaxf(cv[1][0] + pv1.x, 0.f), ctx[4]);
    ctx[5]  = fmaf(p, fmaxf(cv[1][1] + pv1.y, 0.f), ctx[5]);
    ctx[6]  = fmaf(p, fmaxf(cv[1][2] + pv1.z, 0.f), ctx[6]);
    ctx[7]  = fmaf(p, fmaxf(cv[1][3] + pv1.w, 0.f), ctx[7]);
    ctx[8]  = fmaf(p, fmaxf(cv[2][0] + pv2.x, 0.f), ctx[8]);
    ctx[9]  = fmaf(p, fmaxf(cv[2][1] + pv2.y, 0.f), ctx[9]);
    ctx[10] = fmaf(p, fmaxf(cv[2][2] + pv2.z, 0.f), ctx[10]);
    ctx[11] = fmaf(p, fmaxf(cv[2][3] + pv2.w, 0.f), ctx[11]);
    ctx[12] = fmaf(p, fmaxf(cv[3][0] + pv3.x, 0.f), ctx[12]);
    ctx[13] = fmaf(p, fmaxf(cv[3][1] + pv3.y, 0.f), ctx[13]);
    ctx[14] = fmaf(p, fmaxf(cv[3][2] + pv3.z, 0.f), ctx[14]);
    ctx[15] = fmaf(p, fmaxf(cv[3][3] + pv3.w, 0.f), ctx[15]);
  }

  // in-wave flash-merge across the 16 j-columns (xor butterfly over lane&15)
#pragma unroll
  for (int off = 1; off <= 8; off <<= 1) {
    float mo = __shfl_xor(m, off, 64);
    float so = __shfl_xor(s, off, 64);
    float M2 = fmaxf(m, mo);
    float ca = exp2f(m - M2);
    float cb = exp2f(mo - M2);
    s = s * ca + so * cb;
#pragma unroll
    for (int e = 0; e < 16; ++e) {
      float co = __shfl_xor(ctx[e], off, 64);
      ctx[e] = ctx[e] * ca + co * cb;
    }
    m = M2;
  }

  __shared__ float ctxs[2][64];
  __shared__ float mss[2][2];
  if (l15 == 0) {
#pragma unroll
    for (int Mt = 0; Mt < 4; ++Mt)
#pragma unroll
      for (int r = 0; r < 4; ++r) ctxs[w][Mt * 16 + g4 * 4 + r] = ctx[Mt * 4 + r];
  }
  if (lane == 0) {
    mss[w][0] = m;
    mss[w][1] = s;
  }
  __syncthreads();

  if (w == 0) {
    float m0 = mss[0][0], s0 = mss[0][1], m1 = mss[1][0], s1 = mss[1][1];
    float M = fmaxf(m0, m1);
    float e0 = exp2f(m0 - M), e1 = exp2f(m1 - M);
    float S = s0 * e0 + s1 * e1;
    float cm = ctxs[0][lane] * e0 + ctxs[1][lane] * e1;  // unnormalized
    float* dst = half ? Pctx1 : Pctx0;
    dst[i * H + lane] = cm;
    if (lane == 0) {
      Pm[bid] = M;
      Ps[bid] = S;
    }
  }
}

// ---------------- k5: merge two j-half partials + pv_w2 matvec + residual + LN (4 rows/blk)
// NOTE: Pctx1 and enc2 intentionally ALIAS (read-partial-then-overwrite, same element) —
// they must NOT be __restrict__-qualified.
__global__ __launch_bounds__(256) void k_pmerge(
    const float* __restrict__ Pm, const float* __restrict__ Ps,
    const float* __restrict__ Pctx0, const float* Pctx1,
    const float* __restrict__ enc, const float* __restrict__ pv_w2,
    const float* __restrict__ pv_b2, const float* __restrict__ lng,
    const float* __restrict__ lnb, float* enc2) {
  const int sub = threadIdx.x >> 6, lane = threadIdx.x & 63;
  const int i = blockIdx.x * 4 + sub;
  float m0 = Pm[i], s0 = Ps[i], m1 = Pm[N + i], s1 = Ps[N + i];
  float c0 = Pctx0[i * H + lane];
  float c1 = Pctx1[i * H + lane];  // aliases enc2[i*H+lane]; ordered (no restrict)
  float M = fmaxf(m0, m1);
  float e0 = exp2f(m0 - M), e1 = exp2f(m1 - M);
  float S = s0 * e0 + s1 * e1;
  float cp = (c0 * e0 + c1 * e1) / S;
  float pc = pv_b2[lane];
#pragma unroll 8
  for (int k = 0; k < 64; ++k) pc += __shfl(cp, k, 64) * pv_w2[k * H + lane];
  float x = enc[i * H + lane] + pc;
  float mu = wave_reduce_sum(x) * (1.f / 64.f);
  float dd = x - mu;
  float var = wave_reduce_sum(dd * dd) * (1.f / 64.f);
  enc2[i * H + lane] = dd * rsqrtf(var + 1e-5f) * lng[lane] + lnb[lane];
}

// ---------------- k6: score head with in-block column mean (4 rows per block)
__global__ __launch_bounds__(256) void k_score(
    const float* __restrict__ enc2, const float* __restrict__ sh_w1,
    const float* __restrict__ sh_b1, const float* __restrict__ sh_w2,
    const float* __restrict__ sh_b2, float* __restrict__ out) {
  const int sub = threadIdx.x >> 6, lane = threadIdx.x & 63;
  const int row = blockIdx.x * 4 + sub;
  // column sum: wave sub covers rows sub*256 .. sub*256+255
  float cs = 0.f;
  const float* pp = enc2 + (sub * 256) * H + lane;
#pragma unroll 8
  for (int r = 0; r < 256; ++r) cs += pp[r * H];
  __shared__ float part[4][64];
  __shared__ float erow[4][H];
  part[sub][lane] = cs;
  erow[sub][lane] = enc2[row * H + lane];
  __syncthreads();
  float g = (part[0][lane] + part[1][lane] + part[2][lane] + part[3][lane]) * (1.f / N);
  float t = sh_b1[lane];
#pragma unroll 8
  for (int k = 0; k < 64; ++k) {
    t += erow[sub][k] * sh_w1[k * H + lane];
    t += __shfl(g, k, 64) * sh_w1[(64 + k) * H + lane];
  }
  t = fmaxf(t, 0.f);
  float prt = t * sh_w2[lane];
  float sum = wave_reduce_sum(prt);
  if (lane == 0) out[row] = sum + sh_b2[0];
}

extern "C" void kernel_launch(void* const* d_in, const int* in_sizes, int n_in,
                              void* d_out, int out_size, void* d_ws, size_t ws_size,
                              hipStream_t stream) {
  const float* feat = (const float*)d_in[0];
  const float* ip_w1 = (const float*)d_in[1];
  const float* ip_b1 = (const float*)d_in[2];
  const float* ip_ln_g = (const float*)d_in[3];
  const float* ip_ln_b = (const float*)d_in[4];
  const float* ip_w2 = (const float*)d_in[5];
  const float* ip_b2 = (const float*)d_in[6];
  const float* attn_in_w = (const float*)d_in[7];
  const float* attn_in_b = (const float*)d_in[8];
  const float* attn_out_w = (const float*)d_in[9];
  const float* attn_out_b = (const float*)d_in[10];
  const float* attn_ln_g = (const float*)d_in[11];
  const float* attn_ln_b = (const float*)d_in[12];
  const float* pg_w1 = (const float*)d_in[13];
  const float* pg_b1 = (const float*)d_in[14];
  const float* pg_w2 = (const float*)d_in[15];
  const float* pg_b2 = (const float*)d_in[16];
  const float* pv_w1 = (const float*)d_in[17];
  const float* pv_b1 = (const float*)d_in[18];
  const float* pv_w2 = (const float*)d_in[19];
  const float* pv_b2 = (const float*)d_in[20];
  const float* ctx_ln_g = (const float*)d_in[21];
  const float* ctx_ln_b = (const float*)d_in[22];
  const float* sh_w1 = (const float*)d_in[23];
  const float* sh_b1 = (const float*)d_in[24];
  const float* sh_w2 = (const float*)d_in[25];
  const float* sh_b2 = (const float*)d_in[26];

  float* ws = (float*)d_ws;
  // lifetimes: h written k1, read k3 (Av aliases h: k3 same-row read-then-write);
  // Qh/Kh/Vh written k1, read k2, then Pg/Pv/Ag overwrite in k3; o written k2, read k3,
  // then Pctx0 (k4) reuses it; Pctx1 aliases enc2 (k5 reads partial then writes same slot).
  float* h = ws;                        // 0      .. 65536
  float* Qh = ws + 65536;
  float* Kh = ws + 131072;
  float* Vh = ws + 196608;
  float* o = ws + 262144;
  float* enc = ws + 327680;
  float* enc2 = ws + 393216;
  float* Pg = ws + 65536;               // reuse Qh
  float* Pv = ws + 131072;              // reuse Kh
  float* Ag = ws + 196608;              // reuse Vh
  float* Av = ws;                       // reuse h (same-row read-then-write in k3)
  float* Pctx0 = ws + 262144;           // reuse o
  float* Pctx1 = enc2;                  // merge reads partial then overwrites same slot
  float* WgA = ws + 458752;             // 4096 each
  float* WgB = ws + 462848;
  float* WvA = ws + 466944;
  float* WvB = ws + 471040;
  unsigned int* WF = (unsigned int*)(ws + 475136);  // 4096 u32
  float* Pm = ws + 479232;              // 2048
  float* Ps = ws + 481280;              // 2048
  unsigned int* encH = (unsigned int*)(ws + 483328);  // 32768 u32 (f16-packed enc)
  float* out = (float*)d_out;

  k_input_qkv_prep<<<260, 256, 0, stream>>>(feat, ip_w1, ip_b1, ip_ln_g, ip_ln_b, ip_w2,
                                            ip_b2, attn_in_w, attn_in_b, pg_w1, pv_w1, h,
                                            Qh, Kh, Vh, WgA, WgB, WvA, WvB, WF);
  k_attn2<<<1024, 256, 0, stream>>>(Qh, Kh, Vh, o);
  k_attn_ab<<<256, 256, 0, stream>>>(o, attn_out_w, attn_out_b, h, attn_ln_g, attn_ln_b,
                                     WgA, WgB, WvA, WvB, pg_b1, pv_b1, enc, Ag, Av, Pg,
                                     Pv, encH);
  k_pairp<<<2 * N, 128, 0, stream>>>(encH, Ag, Av, WF, Pg, Pv, pg_w2, pg_b2, Pm, Ps,
                                     Pctx0, Pctx1);
  k_pmerge<<<256, 256, 0, stream>>>(Pm, Ps, Pctx0, Pctx1, enc, pv_w2, pv_b2, ctx_ln_g,
                                    ctx_ln_b, enc2);
  k_score<<<256, 256, 0, stream>>>(enc2, sh_w1, sh_b1, sh_w2, sh_b2, out);
}